// Round 3
// baseline (2505.308 us; speedup 1.0000x reference)
//
#include <hip/hip_runtime.h>

#define PI_F 3.14159265358979323846f

struct EdgeGeom { float enc[8]; float h0, h1, h2; };

__device__ __forceinline__ bool edge_geom(const float* __restrict__ r_ij, int e, EdgeGeom& g) {
  const float rx = r_ij[3*e], ry = r_ij[3*e+1], rz = r_ij[3*e+2];
  const float xsq = (rx*rx + ry*ry + rz*rz) * (1.0f/2.5f);
  const float cut = 1.0f - xsq;
  if (cut <= 0.0f) return false;
  const float th = PI_F * sqrtf(xsq);
  const float c1 = cosf(th);
  g.enc[0] = cut; g.enc[1] = c1*cut;
  float cp = 1.0f, cc = c1;
  #pragma unroll
  for (int n = 2; n < 8; n++) { float cn = 2.0f*c1*cc - cp; cp = cc; cc = cn; g.enc[n] = cn*cut; }
  const float s = 7.0f/2.5f;
  const float yx = rx*s, yy = ry*s, yz = rz*s;
  const float inv = rsqrtf(1.0f + yx*yx + yy*yy + yz*yz);
  g.h0 = yx*inv; g.h1 = yy*inv; g.h2 = yz*inv;
  return true;
}

__device__ __forceinline__ int edge_id(const int* __restrict__ cnt, const int* __restrict__ list,
                                       int idx, int E) {
  if (list != nullptr) { if (idx >= *cnt) return -1; return list[idx]; }
  if (idx >= E) return -1;
  return idx;
}

// ---------------- compaction ----------------
__global__ __launch_bounds__(256) void compact_k(const float* __restrict__ r, int E,
                                                 int* __restrict__ cnt, int* __restrict__ list) {
  int e = blockIdx.x * 256 + threadIdx.x;
  if (e >= E) return;
  float rx = r[3*e], ry = r[3*e+1], rz = r[3*e+2];
  float xsq = (rx*rx + ry*ry + rz*rz) * (1.0f/2.5f);
  if (xsq < 1.0f) {
    int p = atomicAdd(cnt, 1);
    list[p] = e;
  }
}

// All msg kernels: 512 threads = 128 edges x 4 slices. VGPR capped at 128 via lb(512,4).
static constexpr int TB  = 512;
static constexpr int EPB = TB / 4;   // edges per block

// ---------------- rank-0: psi_a (slice = 8 of 32 'a' outputs) ----------------
// LDS: P000(8192) | P110(4096) | P220(2048) = 14336 floats (57.3 KB)
__global__ __launch_bounds__(TB, 4) void msgA_k(
    const float* __restrict__ r_ij, const float* __restrict__ x_a,
    const float* __restrict__ x_v,  const float* __restrict__ x_d,
    const float* __restrict__ P000, const float* __restrict__ P110, const float* __restrict__ P220,
    const int* __restrict__ src, const int* __restrict__ dst,
    const int* __restrict__ cnt, const int* __restrict__ list, int E,
    float* __restrict__ outA)
{
  if (list && (blockIdx.x * EPB) >= *cnt) return;   // uniform early-out (before staging)
  __shared__ float sP[14336];
  {
    float4* s4 = (float4*)sP;
    const float4* a4 = (const float4*)P000;
    const float4* b4 = (const float4*)P110;
    const float4* c4 = (const float4*)P220;
    for (int i = threadIdx.x; i < 2048; i += TB) s4[i]        = a4[i];
    for (int i = threadIdx.x; i < 1024; i += TB) s4[2048+i]   = b4[i];
    for (int i = threadIdx.x; i < 512;  i += TB) s4[3072+i]   = c4[i];
  }
  __syncthreads();

  const int idx   = blockIdx.x * EPB + (threadIdx.x >> 2);
  const int slice = threadIdx.x & 3;
  const int e = edge_id(cnt, list, idx, E);
  if (e < 0) return;
  EdgeGeom g;
  if (!edge_geom(r_ij, e, g)) return;

  const int nj = dst[e], ni = src[e];
  const float4* __restrict__ xa4 = (const float4*)(x_a + (size_t)nj*32);
  const float4* __restrict__ xv4 = (const float4*)(x_v + (size_t)nj*48);
  const float4* __restrict__ xd4 = (const float4*)(x_d + (size_t)nj*72);

  // c[56] = [xa (32) | s1 = h.xv (16) | s2 = h^T xd h (8)]
  float c[56];
  #pragma unroll
  for (int q = 0; q < 8; q++) { float4 f = xa4[q]; c[4*q]=f.x; c[4*q+1]=f.y; c[4*q+2]=f.z; c[4*q+3]=f.w; }
  {
    float xv[48];
    #pragma unroll
    for (int q = 0; q < 12; q++) { float4 f = xv4[q]; xv[4*q]=f.x; xv[4*q+1]=f.y; xv[4*q+2]=f.z; xv[4*q+3]=f.w; }
    #pragma unroll
    for (int b = 0; b < 16; b++)
      c[32+b] = g.h0*xv[3*b] + g.h1*xv[3*b+1] + g.h2*xv[3*b+2];
  }
  {
    float xd[72];
    #pragma unroll
    for (int q = 0; q < 18; q++) { float4 f = xd4[q]; xd[4*q]=f.x; xd[4*q+1]=f.y; xd[4*q+2]=f.z; xd[4*q+3]=f.w; }
    #pragma unroll
    for (int b = 0; b < 8; b++) {
      const float* m = xd + 9*b;
      float t0 = g.h0*m[0] + g.h1*m[3] + g.h2*m[6];
      float t1 = g.h0*m[1] + g.h1*m[4] + g.h2*m[7];
      float t2 = g.h0*m[2] + g.h1*m[5] + g.h2*m[8];
      c[48+b] = g.h0*t0 + g.h1*t1 + g.h2*t2;
    }
  }

  float* o = outA + (size_t)ni*32;
  const float* __restrict__ s000 = sP;
  const float* __restrict__ s110 = sP + 8192;
  const float* __restrict__ s220 = sP + 12288;
  const int a0 = slice * 8;
  #pragma unroll 1
  for (int k = 0; k < 8; k++) {
    const int a = a0 + k;
    float acc = 0.0f;
    #pragma unroll
    for (int l = 0; l < 8; l++) {
      const float* p0 = s000 + (a*8 + l)*32;
      const float* p1 = s110 + (a*8 + l)*16;
      const float* p2 = s220 + (a*8 + l)*8;
      float s = 0.0f;
      #pragma unroll
      for (int b = 0; b < 32; b++) s += p0[b]*c[b];
      #pragma unroll
      for (int b = 0; b < 16; b++) s += p1[b]*c[32+b];
      #pragma unroll
      for (int b = 0; b < 8;  b++) s += p2[b]*c[48+b];
      acc += g.enc[l]*s;
    }
    atomicAdd(o + a, 0.1f*acc);
  }
}

// ---------------- rank-1: psi_v (slice = 4 of 16 'v' outputs) ----------------
// LDS: P011(2048)|P101(4096)|P121(1024)|P211(2048)|P111(2048) = 11264 floats (45 KB)
__global__ __launch_bounds__(TB, 4) void msgV_k(
    const float* __restrict__ r_ij, const float* __restrict__ x_a,
    const float* __restrict__ x_v,  const float* __restrict__ x_d,
    const float* __restrict__ P011, const float* __restrict__ P101, const float* __restrict__ P121,
    const float* __restrict__ P211, const float* __restrict__ P111,
    const int* __restrict__ src, const int* __restrict__ dst,
    const int* __restrict__ cnt, const int* __restrict__ list, int E,
    float* __restrict__ outV)
{
  if (list && (blockIdx.x * EPB) >= *cnt) return;
  __shared__ float sP[11264];
  {
    float4* s4 = (float4*)sP;
    for (int i = threadIdx.x; i < 512;  i += TB) s4[i]        = ((const float4*)P011)[i];
    for (int i = threadIdx.x; i < 1024; i += TB) s4[512+i]    = ((const float4*)P101)[i];
    for (int i = threadIdx.x; i < 256;  i += TB) s4[1536+i]   = ((const float4*)P121)[i];
    for (int i = threadIdx.x; i < 512;  i += TB) s4[1792+i]   = ((const float4*)P211)[i];
    for (int i = threadIdx.x; i < 512;  i += TB) s4[2304+i]   = ((const float4*)P111)[i];
  }
  __syncthreads();

  const int idx   = blockIdx.x * EPB + (threadIdx.x >> 2);
  const int slice = threadIdx.x & 3;
  const int e = edge_id(cnt, list, idx, E);
  if (e < 0) return;
  EdgeGeom g;
  if (!edge_geom(r_ij, e, g)) return;

  const int nj = dst[e], ni = src[e];
  const float4* __restrict__ xa4 = (const float4*)(x_a + (size_t)nj*32);
  const float4* __restrict__ xv4 = (const float4*)(x_v + (size_t)nj*48);
  const float4* __restrict__ xd4 = (const float4*)(x_d + (size_t)nj*72);

  const float* __restrict__ s011 = sP;
  const float* __restrict__ s101 = sP + 2048;
  const float* __restrict__ s121 = sP + 6144;
  const float* __restrict__ s211 = sP + 7168;
  const float* __restrict__ s111 = sP + 9216;

  const int v0 = slice * 4;

  // V channel + s1
  float V0[16], V1[16], V2[16], s1[16];
  {
    float xv[48];
    #pragma unroll
    for (int q = 0; q < 12; q++) { float4 f = xv4[q]; xv[4*q]=f.x; xv[4*q+1]=f.y; xv[4*q+2]=f.z; xv[4*q+3]=f.w; }
    #pragma unroll
    for (int b = 0; b < 16; b++) {
      V0[b]=xv[3*b]; V1[b]=xv[3*b+1]; V2[b]=xv[3*b+2];
      s1[b] = g.h0*V0[b] + g.h1*V1[b] + g.h2*V2[b];
    }
  }

  // phase 1: scv[4]
  float scv[4];
  {
    float xa[32];
    #pragma unroll
    for (int q = 0; q < 8; q++) { float4 f = xa4[q]; xa[4*q]=f.x; xa[4*q+1]=f.y; xa[4*q+2]=f.z; xa[4*q+3]=f.w; }
    #pragma unroll 1
    for (int k = 0; k < 4; k++) {
      const int v = v0 + k;
      float acc = 0.0f;
      #pragma unroll
      for (int l = 0; l < 8; l++) {
        const float* pa = s101 + (v*8 + l)*32;
        const float* pb = s211 + (v*8 + l)*16;
        float s = 0.0f;
        #pragma unroll
        for (int b = 0; b < 32; b++) s += pa[b]*xa[b];
        #pragma unroll
        for (int b = 0; b < 16; b++) s += pb[b]*s1[b];
        acc += g.enc[l]*s;
      }
      scv[k] = acc;
    }
  }

  // T = h^T xd
  float T0[8], T1[8], T2v[8];
  {
    float xd[72];
    #pragma unroll
    for (int q = 0; q < 18; q++) { float4 f = xd4[q]; xd[4*q]=f.x; xd[4*q+1]=f.y; xd[4*q+2]=f.z; xd[4*q+3]=f.w; }
    #pragma unroll
    for (int b = 0; b < 8; b++) {
      const float* m = xd + 9*b;
      T0[b]  = g.h0*m[0] + g.h1*m[3] + g.h2*m[6];
      T1[b]  = g.h0*m[1] + g.h1*m[4] + g.h2*m[7];
      T2v[b] = g.h0*m[2] + g.h1*m[5] + g.h2*m[8];
    }
  }

  // phase 2: A = sum enc*(P011.V + P121.T), W = sum enc*(P111.V); out = A + h x W + h*scv
  float* o = outV + (size_t)ni*48;
  #pragma unroll 1
  for (int k = 0; k < 4; k++) {
    const int v = v0 + k;
    float A0=0, A1=0, A2=0, W0=0, W1=0, W2=0;
    #pragma unroll
    for (int l = 0; l < 8; l++) {
      const float el = g.enc[l];
      const float* p011 = s011 + (v*8 + l)*16;
      const float* p121 = s121 + (v*8 + l)*8;
      const float* p111 = s111 + (v*8 + l)*16;
      float a0=0, a1=0, a2=0, w0=0, w1=0, w2=0;
      #pragma unroll
      for (int b = 0; b < 16; b++) { float p = p011[b]; a0 += p*V0[b]; a1 += p*V1[b]; a2 += p*V2[b]; }
      #pragma unroll
      for (int b = 0; b < 8;  b++) { float p = p121[b]; a0 += p*T0[b]; a1 += p*T1[b]; a2 += p*T2v[b]; }
      #pragma unroll
      for (int b = 0; b < 16; b++) { float p = p111[b]; w0 += p*V0[b]; w1 += p*V1[b]; w2 += p*V2[b]; }
      A0 += el*a0; A1 += el*a1; A2 += el*a2;
      W0 += el*w0; W1 += el*w1; W2 += el*w2;
    }
    const float sv = scv[k];
    atomicAdd(o + v*3 + 0, 0.1f*(A0 + (g.h1*W2 - g.h2*W1) + g.h0*sv));
    atomicAdd(o + v*3 + 1, 0.1f*(A1 + (g.h2*W0 - g.h0*W2) + g.h1*sv));
    atomicAdd(o + v*3 + 2, 0.1f*(A2 + (g.h0*W1 - g.h1*W0) + g.h2*sv));
  }
}

// ---------------- rank-2: psi_d (slice = 2 of 8 'd' outputs) ----------------
// LDS: P022(512)|P202(2048)|P112(1024)|P222(512)|P212(1024) = 5120 floats (20 KB)
__global__ __launch_bounds__(TB, 4) void msgD_k(
    const float* __restrict__ r_ij, const float* __restrict__ x_a,
    const float* __restrict__ x_v,  const float* __restrict__ x_d,
    const float* __restrict__ P022, const float* __restrict__ P202, const float* __restrict__ P112,
    const float* __restrict__ P222, const float* __restrict__ P212,
    const int* __restrict__ src, const int* __restrict__ dst,
    const int* __restrict__ cnt, const int* __restrict__ list, int E,
    float* __restrict__ outD)
{
  if (list && (blockIdx.x * EPB) >= *cnt) return;
  __shared__ float sP[5120];
  {
    float4* s4 = (float4*)sP;
    for (int i = threadIdx.x; i < 128;  i += TB) s4[i]        = ((const float4*)P022)[i];
    for (int i = threadIdx.x; i < 512;  i += TB) s4[128+i]    = ((const float4*)P202)[i];
    for (int i = threadIdx.x; i < 256;  i += TB) s4[640+i]    = ((const float4*)P112)[i];
    for (int i = threadIdx.x; i < 128;  i += TB) s4[896+i]    = ((const float4*)P222)[i];
    for (int i = threadIdx.x; i < 256;  i += TB) s4[1024+i]   = ((const float4*)P212)[i];
  }
  __syncthreads();

  const int idx   = blockIdx.x * EPB + (threadIdx.x >> 2);
  const int slice = threadIdx.x & 3;
  const int e = edge_id(cnt, list, idx, E);
  if (e < 0) return;
  EdgeGeom g;
  if (!edge_geom(r_ij, e, g)) return;

  const int nj = dst[e], ni = src[e];
  const float4* __restrict__ xa4 = (const float4*)(x_a + (size_t)nj*32);
  const float4* __restrict__ xv4 = (const float4*)(x_v + (size_t)nj*48);
  const float4* __restrict__ xd4 = (const float4*)(x_d + (size_t)nj*72);

  const float* __restrict__ s022 = sP;
  const float* __restrict__ s202 = sP + 512;
  const float* __restrict__ s112 = sP + 2560;
  const float* __restrict__ s222 = sP + 3584;
  const float* __restrict__ s212 = sP + 4096;

  const int d0 = slice * 2;

  // scd[2] from xa
  float scd[2];
  {
    float xa[32];
    #pragma unroll
    for (int q = 0; q < 8; q++) { float4 f = xa4[q]; xa[4*q]=f.x; xa[4*q+1]=f.y; xa[4*q+2]=f.z; xa[4*q+3]=f.w; }
    #pragma unroll 1
    for (int k = 0; k < 2; k++) {
      const int d = d0 + k;
      float acc = 0.0f;
      #pragma unroll
      for (int l = 0; l < 8; l++) {
        const float* p = s202 + (d*8 + l)*32;
        float s = 0.0f;
        #pragma unroll
        for (int b = 0; b < 32; b++) s += p[b]*xa[b];
        acc += g.enc[l]*s;
      }
      scd[k] = acc;
    }
  }

  // Q[2][3]: A + h x W over V and T channels
  float Q0[2], Q1[2], Q2[2];
  {
    float V0[16], V1[16], V2[16];
    {
      float xv[48];
      #pragma unroll
      for (int q = 0; q < 12; q++) { float4 f = xv4[q]; xv[4*q]=f.x; xv[4*q+1]=f.y; xv[4*q+2]=f.z; xv[4*q+3]=f.w; }
      #pragma unroll
      for (int b = 0; b < 16; b++) { V0[b]=xv[3*b]; V1[b]=xv[3*b+1]; V2[b]=xv[3*b+2]; }
    }
    float T0[8], T1[8], T2v[8];
    {
      float xd[72];
      #pragma unroll
      for (int q = 0; q < 18; q++) { float4 f = xd4[q]; xd[4*q]=f.x; xd[4*q+1]=f.y; xd[4*q+2]=f.z; xd[4*q+3]=f.w; }
      #pragma unroll
      for (int b = 0; b < 8; b++) {
        const float* m = xd + 9*b;
        T0[b]  = g.h0*m[0] + g.h1*m[3] + g.h2*m[6];
        T1[b]  = g.h0*m[1] + g.h1*m[4] + g.h2*m[7];
        T2v[b] = g.h0*m[2] + g.h1*m[5] + g.h2*m[8];
      }
    }
    #pragma unroll 1
    for (int k = 0; k < 2; k++) {
      const int d = d0 + k;
      float A0=0, A1=0, A2=0, W0=0, W1=0, W2=0;
      #pragma unroll
      for (int l = 0; l < 8; l++) {
        const float el = g.enc[l];
        const float* p112 = s112 + (d*8 + l)*16;
        const float* p222 = s222 + (d*8 + l)*8;
        const float* p212 = s212 + (d*8 + l)*16;
        float a0=0, a1=0, a2=0, w0=0, w1=0, w2=0;
        #pragma unroll
        for (int b = 0; b < 16; b++) { float p = p112[b]; a0 += p*V0[b]; a1 += p*V1[b]; a2 += p*V2[b]; }
        #pragma unroll
        for (int b = 0; b < 8;  b++) { float p = p222[b]; a0 += p*T0[b]; a1 += p*T1[b]; a2 += p*T2v[b]; }
        #pragma unroll
        for (int b = 0; b < 16; b++) { float p = p212[b]; w0 += p*V0[b]; w1 += p*V1[b]; w2 += p*V2[b]; }
        A0 += el*a0; A1 += el*a1; A2 += el*a2;
        W0 += el*w0; W1 += el*w1; W2 += el*w2;
      }
      Q0[k] = A0 + (g.h1*W2 - g.h2*W1);
      Q1[k] = A1 + (g.h2*W0 - g.h0*W2);
      Q2[k] = A2 + (g.h0*W1 - g.h1*W0);
    }
  }

  // psi_d = sum enc*P022 (x) X + h_i Q_j + h_i h_j scd
  float X[8][9];
  {
    float xd[72];
    #pragma unroll
    for (int q = 0; q < 18; q++) { float4 f = xd4[q]; xd[4*q]=f.x; xd[4*q+1]=f.y; xd[4*q+2]=f.z; xd[4*q+3]=f.w; }
    #pragma unroll
    for (int b = 0; b < 8; b++)
      #pragma unroll
      for (int kk = 0; kk < 9; kk++) X[b][kk] = xd[9*b + kk];
  }
  const float hh[3] = { g.h0, g.h1, g.h2 };
  float* o = outD + (size_t)ni*72;
  #pragma unroll 1
  for (int k = 0; k < 2; k++) {
    const int d = d0 + k;
    float acc[9] = {0,0,0,0,0,0,0,0,0};
    #pragma unroll
    for (int l = 0; l < 8; l++) {
      const float el = g.enc[l];
      const float* p = s022 + (d*8 + l)*8;
      #pragma unroll
      for (int b = 0; b < 8; b++) {
        const float pe = el*p[b];
        #pragma unroll
        for (int kk = 0; kk < 9; kk++) acc[kk] += pe*X[b][kk];
      }
    }
    const float sd = scd[k];
    const float q[3] = { Q0[k], Q1[k], Q2[k] };
    #pragma unroll
    for (int i = 0; i < 3; i++) {
      const float hi = hh[i];
      #pragma unroll
      for (int j = 0; j < 3; j++) {
        atomicAdd(o + d*9 + 3*i + j, 0.1f*(acc[3*i + j] + hi*q[j] + hi*hh[j]*sd));
      }
    }
  }
}

extern "C" void kernel_launch(void* const* d_in, const int* in_sizes, int n_in,
                              void* d_out, int out_size, void* d_ws, size_t ws_size,
                              hipStream_t stream) {
  const float* r_ij = (const float*)d_in[0];
  const float* x_a  = (const float*)d_in[1];
  const float* x_v  = (const float*)d_in[2];
  const float* x_d  = (const float*)d_in[3];
  const float* P000 = (const float*)d_in[4];
  const float* P110 = (const float*)d_in[5];
  const float* P220 = (const float*)d_in[6];
  const float* P011 = (const float*)d_in[7];
  const float* P101 = (const float*)d_in[8];
  const float* P121 = (const float*)d_in[9];
  const float* P211 = (const float*)d_in[10];
  const float* P111 = (const float*)d_in[11];
  const float* P022 = (const float*)d_in[12];
  const float* P202 = (const float*)d_in[13];
  const float* P112 = (const float*)d_in[14];
  const float* P222 = (const float*)d_in[15];
  const float* P212 = (const float*)d_in[16];
  const int* src = (const int*)d_in[17];
  const int* dst = (const int*)d_in[18];

  const int E = in_sizes[17];
  const int N = in_sizes[1] / 32;
  float* out = (float*)d_out;
  float* outA = out;
  float* outV = out + (size_t)N*32;
  float* outD = out + (size_t)N*80;

  hipMemsetAsync(d_out, 0, (size_t)out_size * sizeof(float), stream);

  const size_t need = 256 + (size_t)E * sizeof(int);
  int* cnt = nullptr;
  int* list = nullptr;
  if (ws_size >= need) {
    cnt  = (int*)d_ws;
    list = (int*)((char*)d_ws + 256);
    hipMemsetAsync(d_ws, 0, 256, stream);
    compact_k<<<(E + 255)/256, 256, 0, stream>>>(r_ij, E, cnt, list);
  }

  const int grid = (E + EPB - 1) / EPB;
  msgA_k<<<grid, TB, 0, stream>>>(r_ij, x_a, x_v, x_d,
      P000, P110, P220, src, dst, cnt, list, E, outA);
  msgV_k<<<grid, TB, 0, stream>>>(r_ij, x_a, x_v, x_d,
      P011, P101, P121, P211, P111, src, dst, cnt, list, E, outV);
  msgD_k<<<grid, TB, 0, stream>>>(r_ij, x_a, x_v, x_d,
      P022, P202, P112, P222, P212, src, dst, cnt, list, E, outD);
}

// Round 4
// 1908.365 us; speedup vs baseline: 1.3128x; 1.3128x over previous
//
#include <hip/hip_runtime.h>

#define PI_F 3.14159265358979323846f

struct EdgeGeom { float enc[8]; float h0, h1, h2; };

__device__ __forceinline__ bool edge_geom(const float* __restrict__ r_ij, int e, EdgeGeom& g) {
  const float rx = r_ij[3*e], ry = r_ij[3*e+1], rz = r_ij[3*e+2];
  const float xsq = (rx*rx + ry*ry + rz*rz) * (1.0f/2.5f);
  const float cut = 1.0f - xsq;
  if (cut <= 0.0f) return false;
  const float th = PI_F * sqrtf(xsq);
  const float c1 = cosf(th);
  g.enc[0] = cut; g.enc[1] = c1*cut;
  float cp = 1.0f, cc = c1;
  #pragma unroll
  for (int n = 2; n < 8; n++) { float cn = 2.0f*c1*cc - cp; cp = cc; cc = cn; g.enc[n] = cn*cut; }
  const float s = 7.0f/2.5f;
  const float yx = rx*s, yy = ry*s, yz = rz*s;
  const float inv = rsqrtf(1.0f + yx*yx + yy*yy + yz*yz);
  g.h0 = yx*inv; g.h1 = yy*inv; g.h2 = yz*inv;
  return true;
}

__device__ __forceinline__ int edge_id(const int* __restrict__ cnt, const int* __restrict__ list,
                                       int idx, int E) {
  if (list != nullptr) { if (idx >= *cnt) return -1; return list[idx]; }
  if (idx >= E) return -1;
  return idx;
}

__global__ __launch_bounds__(256) void compact_k(const float* __restrict__ r, int E,
                                                 int* __restrict__ cnt, int* __restrict__ list) {
  int e = blockIdx.x * 256 + threadIdx.x;
  if (e >= E) return;
  float rx = r[3*e], ry = r[3*e+1], rz = r[3*e+2];
  float xsq = (rx*rx + ry*ry + rz*rz) * (1.0f/2.5f);
  if (xsq < 1.0f) {
    int p = atomicAdd(cnt, 1);
    list[p] = e;
  }
}

// ---------------- rank-0: psi_a. 1 thread = 1 edge. LDS 57 KB, lb(512,4): cap 128 VGPR ----------------
__global__ __launch_bounds__(512, 4) void msgA_k(
    const float* __restrict__ r_ij, const float* __restrict__ x_a,
    const float* __restrict__ x_v,  const float* __restrict__ x_d,
    const float* __restrict__ P000, const float* __restrict__ P110, const float* __restrict__ P220,
    const int* __restrict__ src, const int* __restrict__ dst,
    const int* __restrict__ cnt, const int* __restrict__ list, int E,
    float* __restrict__ outA)
{
  if (list && (blockIdx.x * 512) >= *cnt) return;
  __shared__ float sP[14336];
  {
    float4* s4 = (float4*)sP;
    for (int i = threadIdx.x; i < 2048; i += 512) s4[i]      = ((const float4*)P000)[i];
    for (int i = threadIdx.x; i < 1024; i += 512) s4[2048+i] = ((const float4*)P110)[i];
    for (int i = threadIdx.x; i < 512;  i += 512) s4[3072+i] = ((const float4*)P220)[i];
  }
  __syncthreads();

  const int idx = blockIdx.x * 512 + threadIdx.x;
  const int e = edge_id(cnt, list, idx, E);
  if (e < 0) return;
  EdgeGeom g;
  if (!edge_geom(r_ij, e, g)) return;

  const int nj = dst[e], ni = src[e];
  const float4* __restrict__ xa4 = (const float4*)(x_a + (size_t)nj*32);
  const float4* __restrict__ xv4 = (const float4*)(x_v + (size_t)nj*48);
  const float*  __restrict__ xdj = x_d + (size_t)nj*72;

  // c[56] = [xa(32) | s1 = h.xv (16) | s2 = h^T xd h (8)]
  float c[56];
  #pragma unroll
  for (int q = 0; q < 8; q++) { float4 f = xa4[q]; c[4*q]=f.x; c[4*q+1]=f.y; c[4*q+2]=f.z; c[4*q+3]=f.w; }
  #pragma unroll
  for (int q = 0; q < 4; q++) {
    float4 f0 = xv4[3*q], f1 = xv4[3*q+1], f2 = xv4[3*q+2];
    c[32+4*q+0] = g.h0*f0.x + g.h1*f0.y + g.h2*f0.z;
    c[32+4*q+1] = g.h0*f0.w + g.h1*f1.x + g.h2*f1.y;
    c[32+4*q+2] = g.h0*f1.z + g.h1*f1.w + g.h2*f2.x;
    c[32+4*q+3] = g.h0*f2.y + g.h1*f2.z + g.h2*f2.w;
  }
  #pragma unroll
  for (int b = 0; b < 8; b++) {
    const float* m = xdj + 9*b;
    float t0 = g.h0*m[0] + g.h1*m[3] + g.h2*m[6];
    float t1 = g.h0*m[1] + g.h1*m[4] + g.h2*m[7];
    float t2 = g.h0*m[2] + g.h1*m[5] + g.h2*m[8];
    c[48+b] = g.h0*t0 + g.h1*t1 + g.h2*t2;
  }

  float* o = outA + (size_t)ni*32;
  #pragma unroll 1
  for (int a = 0; a < 32; a++) {
    float acc = 0.0f;
    #pragma unroll
    for (int l = 0; l < 8; l++) {
      const float4* p0 = (const float4*)(sP +         (a*8 + l)*32);
      const float4* p1 = (const float4*)(sP + 8192  + (a*8 + l)*16);
      const float4* p2 = (const float4*)(sP + 12288 + (a*8 + l)*8);
      float u0=0, u1=0, u2=0, u3=0;
      #pragma unroll
      for (int q = 0; q < 8; q++) {
        float4 f = p0[q];
        u0 += f.x*c[4*q]; u1 += f.y*c[4*q+1]; u2 += f.z*c[4*q+2]; u3 += f.w*c[4*q+3];
      }
      #pragma unroll
      for (int q = 0; q < 4; q++) {
        float4 f = p1[q];
        u0 += f.x*c[32+4*q]; u1 += f.y*c[32+4*q+1]; u2 += f.z*c[32+4*q+2]; u3 += f.w*c[32+4*q+3];
      }
      #pragma unroll
      for (int q = 0; q < 2; q++) {
        float4 f = p2[q];
        u0 += f.x*c[48+4*q]; u1 += f.y*c[48+4*q+1]; u2 += f.z*c[48+4*q+2]; u3 += f.w*c[48+4*q+3];
      }
      acc += g.enc[l]*((u0+u1)+(u2+u3));
    }
    atomicAdd(o + a, 0.1f*acc);
  }
}

// ---------------- rank-1: psi_v. 1 thread = 1 edge. LDS 45 KB, lb(256,3): cap 168 VGPR ----------------
__global__ __launch_bounds__(256, 3) void msgV_k(
    const float* __restrict__ r_ij, const float* __restrict__ x_a,
    const float* __restrict__ x_v,  const float* __restrict__ x_d,
    const float* __restrict__ P011, const float* __restrict__ P101, const float* __restrict__ P121,
    const float* __restrict__ P211, const float* __restrict__ P111,
    const int* __restrict__ src, const int* __restrict__ dst,
    const int* __restrict__ cnt, const int* __restrict__ list, int E,
    float* __restrict__ outV)
{
  if (list && (blockIdx.x * 256) >= *cnt) return;
  __shared__ float sP[11264];
  {
    float4* s4 = (float4*)sP;
    for (int i = threadIdx.x; i < 512;  i += 256) s4[i]      = ((const float4*)P011)[i];
    for (int i = threadIdx.x; i < 1024; i += 256) s4[512+i]  = ((const float4*)P101)[i];
    for (int i = threadIdx.x; i < 256;  i += 256) s4[1536+i] = ((const float4*)P121)[i];
    for (int i = threadIdx.x; i < 512;  i += 256) s4[1792+i] = ((const float4*)P211)[i];
    for (int i = threadIdx.x; i < 512;  i += 256) s4[2304+i] = ((const float4*)P111)[i];
  }
  __syncthreads();

  const int idx = blockIdx.x * 256 + threadIdx.x;
  const int e = edge_id(cnt, list, idx, E);
  if (e < 0) return;
  EdgeGeom g;
  if (!edge_geom(r_ij, e, g)) return;

  const int nj = dst[e], ni = src[e];
  const float4* __restrict__ xa4 = (const float4*)(x_a + (size_t)nj*32);
  const float4* __restrict__ xv4 = (const float4*)(x_v + (size_t)nj*48);
  const float*  __restrict__ xdj = x_d + (size_t)nj*72;

  // s1 = h . xv
  float s1[16];
  #pragma unroll
  for (int q = 0; q < 4; q++) {
    float4 f0 = xv4[3*q], f1 = xv4[3*q+1], f2 = xv4[3*q+2];
    s1[4*q+0] = g.h0*f0.x + g.h1*f0.y + g.h2*f0.z;
    s1[4*q+1] = g.h0*f0.w + g.h1*f1.x + g.h2*f1.y;
    s1[4*q+2] = g.h0*f1.z + g.h1*f1.w + g.h2*f2.x;
    s1[4*q+3] = g.h0*f2.y + g.h1*f2.z + g.h2*f2.w;
  }

  // phase 1: scv[v] = sum_l enc_l (P101.xa + P211.s1)
  float scv[16];
  {
    float xa[32];
    #pragma unroll
    for (int q = 0; q < 8; q++) { float4 f = xa4[q]; xa[4*q]=f.x; xa[4*q+1]=f.y; xa[4*q+2]=f.z; xa[4*q+3]=f.w; }
    #pragma unroll 1
    for (int v = 0; v < 16; v++) {
      float acc = 0.0f;
      #pragma unroll
      for (int l = 0; l < 8; l++) {
        const float4* pa = (const float4*)(sP + 2048 + (v*8 + l)*32);
        const float4* pb = (const float4*)(sP + 7168 + (v*8 + l)*16);
        float u0=0, u1=0, u2=0, u3=0;
        #pragma unroll
        for (int q = 0; q < 8; q++) {
          float4 f = pa[q];
          u0 += f.x*xa[4*q]; u1 += f.y*xa[4*q+1]; u2 += f.z*xa[4*q+2]; u3 += f.w*xa[4*q+3];
        }
        #pragma unroll
        for (int q = 0; q < 4; q++) {
          float4 f = pb[q];
          u0 += f.x*s1[4*q]; u1 += f.y*s1[4*q+1]; u2 += f.z*s1[4*q+2]; u3 += f.w*s1[4*q+3];
        }
        acc += g.enc[l]*((u0+u1)+(u2+u3));
      }
      scv[v] = acc;
    }
  }

  // V channel + T = h^T xd
  float V0[16], V1[16], V2[16];
  #pragma unroll
  for (int q = 0; q < 4; q++) {
    float4 f0 = xv4[3*q], f1 = xv4[3*q+1], f2 = xv4[3*q+2];
    V0[4*q+0]=f0.x; V1[4*q+0]=f0.y; V2[4*q+0]=f0.z;
    V0[4*q+1]=f0.w; V1[4*q+1]=f1.x; V2[4*q+1]=f1.y;
    V0[4*q+2]=f1.z; V1[4*q+2]=f1.w; V2[4*q+2]=f2.x;
    V0[4*q+3]=f2.y; V1[4*q+3]=f2.z; V2[4*q+3]=f2.w;
  }
  float T0[8], T1[8], T2[8];
  #pragma unroll
  for (int b = 0; b < 8; b++) {
    const float* m = xdj + 9*b;
    T0[b] = g.h0*m[0] + g.h1*m[3] + g.h2*m[6];
    T1[b] = g.h0*m[1] + g.h1*m[4] + g.h2*m[7];
    T2[b] = g.h0*m[2] + g.h1*m[5] + g.h2*m[8];
  }

  // phase 2 (factored): w[b] = sum_l enc_l P[v,l,b]; then dot with V/T components
  float* o = outV + (size_t)ni*48;
  #pragma unroll 1
  for (int v = 0; v < 16; v++) {
    // A-part: P011 (V) + P121 (T)
    float w1[16], w2[8];
    #pragma unroll
    for (int b = 0; b < 16; b++) w1[b] = 0.0f;
    #pragma unroll
    for (int b = 0; b < 8; b++)  w2[b] = 0.0f;
    #pragma unroll
    for (int l = 0; l < 8; l++) {
      const float el = g.enc[l];
      const float4* pa = (const float4*)(sP +        (v*8 + l)*16);
      const float4* pb = (const float4*)(sP + 6144 + (v*8 + l)*8);
      #pragma unroll
      for (int q = 0; q < 4; q++) {
        float4 f = pa[q];
        w1[4*q]+=el*f.x; w1[4*q+1]+=el*f.y; w1[4*q+2]+=el*f.z; w1[4*q+3]+=el*f.w;
      }
      #pragma unroll
      for (int q = 0; q < 2; q++) {
        float4 f = pb[q];
        w2[4*q]+=el*f.x; w2[4*q+1]+=el*f.y; w2[4*q+2]+=el*f.z; w2[4*q+3]+=el*f.w;
      }
    }
    float A0=0, A1=0, A2=0;
    #pragma unroll
    for (int b = 0; b < 16; b++) { float w = w1[b]; A0 += w*V0[b]; A1 += w*V1[b]; A2 += w*V2[b]; }
    #pragma unroll
    for (int b = 0; b < 8; b++)  { float w = w2[b]; A0 += w*T0[b]; A1 += w*T1[b]; A2 += w*T2[b]; }

    // W-part: P111 (V), output via h x W
    float w3[16];
    #pragma unroll
    for (int b = 0; b < 16; b++) w3[b] = 0.0f;
    #pragma unroll
    for (int l = 0; l < 8; l++) {
      const float el = g.enc[l];
      const float4* pc = (const float4*)(sP + 9216 + (v*8 + l)*16);
      #pragma unroll
      for (int q = 0; q < 4; q++) {
        float4 f = pc[q];
        w3[4*q]+=el*f.x; w3[4*q+1]+=el*f.y; w3[4*q+2]+=el*f.z; w3[4*q+3]+=el*f.w;
      }
    }
    float W0=0, W1=0, W2=0;
    #pragma unroll
    for (int b = 0; b < 16; b++) { float w = w3[b]; W0 += w*V0[b]; W1 += w*V1[b]; W2 += w*V2[b]; }

    const float sv = scv[v];
    atomicAdd(o + v*3 + 0, 0.1f*(A0 + (g.h1*W2 - g.h2*W1) + g.h0*sv));
    atomicAdd(o + v*3 + 1, 0.1f*(A1 + (g.h2*W0 - g.h0*W2) + g.h1*sv));
    atomicAdd(o + v*3 + 2, 0.1f*(A2 + (g.h0*W1 - g.h1*W0) + g.h2*sv));
  }
}

// ---------------- rank-2: psi_d. 1 thread = 1 edge. LDS 20 KB, lb(256,3): cap 168 VGPR ----------------
__global__ __launch_bounds__(256, 3) void msgD_k(
    const float* __restrict__ r_ij, const float* __restrict__ x_a,
    const float* __restrict__ x_v,  const float* __restrict__ x_d,
    const float* __restrict__ P022, const float* __restrict__ P202, const float* __restrict__ P112,
    const float* __restrict__ P222, const float* __restrict__ P212,
    const int* __restrict__ src, const int* __restrict__ dst,
    const int* __restrict__ cnt, const int* __restrict__ list, int E,
    float* __restrict__ outD)
{
  if (list && (blockIdx.x * 256) >= *cnt) return;
  __shared__ float sP[5120];
  {
    float4* s4 = (float4*)sP;
    for (int i = threadIdx.x; i < 128;  i += 256) s4[i]      = ((const float4*)P022)[i];
    for (int i = threadIdx.x; i < 512;  i += 256) s4[128+i]  = ((const float4*)P202)[i];
    for (int i = threadIdx.x; i < 256;  i += 256) s4[640+i]  = ((const float4*)P112)[i];
    for (int i = threadIdx.x; i < 128;  i += 256) s4[896+i]  = ((const float4*)P222)[i];
    for (int i = threadIdx.x; i < 256;  i += 256) s4[1024+i] = ((const float4*)P212)[i];
  }
  __syncthreads();

  const int idx = blockIdx.x * 256 + threadIdx.x;
  const int e = edge_id(cnt, list, idx, E);
  if (e < 0) return;
  EdgeGeom g;
  if (!edge_geom(r_ij, e, g)) return;

  const int nj = dst[e], ni = src[e];
  const float4* __restrict__ xa4 = (const float4*)(x_a + (size_t)nj*32);
  const float4* __restrict__ xv4 = (const float4*)(x_v + (size_t)nj*48);
  const float*  __restrict__ xdj = x_d + (size_t)nj*72;
  const float4* __restrict__ xd4 = (const float4*)xdj;

  // phase 1: scd[d] = sum_l enc_l (P202 . xa)
  float scd[8];
  {
    float xa[32];
    #pragma unroll
    for (int q = 0; q < 8; q++) { float4 f = xa4[q]; xa[4*q]=f.x; xa[4*q+1]=f.y; xa[4*q+2]=f.z; xa[4*q+3]=f.w; }
    #pragma unroll 1
    for (int d = 0; d < 8; d++) {
      float acc = 0.0f;
      #pragma unroll
      for (int l = 0; l < 8; l++) {
        const float4* p = (const float4*)(sP + 512 + (d*8 + l)*32);
        float u0=0, u1=0, u2=0, u3=0;
        #pragma unroll
        for (int q = 0; q < 8; q++) {
          float4 f = p[q];
          u0 += f.x*xa[4*q]; u1 += f.y*xa[4*q+1]; u2 += f.z*xa[4*q+2]; u3 += f.w*xa[4*q+3];
        }
        acc += g.enc[l]*((u0+u1)+(u2+u3));
      }
      scd[d] = acc;
    }
  }

  // phase 2: V, T, then Q[d] (factored)
  float V0[16], V1[16], V2[16];
  #pragma unroll
  for (int q = 0; q < 4; q++) {
    float4 f0 = xv4[3*q], f1 = xv4[3*q+1], f2 = xv4[3*q+2];
    V0[4*q+0]=f0.x; V1[4*q+0]=f0.y; V2[4*q+0]=f0.z;
    V0[4*q+1]=f0.w; V1[4*q+1]=f1.x; V2[4*q+1]=f1.y;
    V0[4*q+2]=f1.z; V1[4*q+2]=f1.w; V2[4*q+2]=f2.x;
    V0[4*q+3]=f2.y; V1[4*q+3]=f2.z; V2[4*q+3]=f2.w;
  }
  float T0[8], T1[8], T2[8];
  #pragma unroll
  for (int b = 0; b < 8; b++) {
    const float* m = xdj + 9*b;
    T0[b] = g.h0*m[0] + g.h1*m[3] + g.h2*m[6];
    T1[b] = g.h0*m[1] + g.h1*m[4] + g.h2*m[7];
    T2[b] = g.h0*m[2] + g.h1*m[5] + g.h2*m[8];
  }
  float Q0[8], Q1[8], Q2[8];
  #pragma unroll 1
  for (int d = 0; d < 8; d++) {
    // A-part: P112 (V) + P222 (T)
    float w1[16], w2[8];
    #pragma unroll
    for (int b = 0; b < 16; b++) w1[b] = 0.0f;
    #pragma unroll
    for (int b = 0; b < 8; b++)  w2[b] = 0.0f;
    #pragma unroll
    for (int l = 0; l < 8; l++) {
      const float el = g.enc[l];
      const float4* pa = (const float4*)(sP + 2560 + (d*8 + l)*16);
      const float4* pb = (const float4*)(sP + 3584 + (d*8 + l)*8);
      #pragma unroll
      for (int q = 0; q < 4; q++) {
        float4 f = pa[q];
        w1[4*q]+=el*f.x; w1[4*q+1]+=el*f.y; w1[4*q+2]+=el*f.z; w1[4*q+3]+=el*f.w;
      }
      #pragma unroll
      for (int q = 0; q < 2; q++) {
        float4 f = pb[q];
        w2[4*q]+=el*f.x; w2[4*q+1]+=el*f.y; w2[4*q+2]+=el*f.z; w2[4*q+3]+=el*f.w;
      }
    }
    float A0=0, A1=0, A2=0;
    #pragma unroll
    for (int b = 0; b < 16; b++) { float w = w1[b]; A0 += w*V0[b]; A1 += w*V1[b]; A2 += w*V2[b]; }
    #pragma unroll
    for (int b = 0; b < 8; b++)  { float w = w2[b]; A0 += w*T0[b]; A1 += w*T1[b]; A2 += w*T2[b]; }

    // W-part: P212 (V), via h x W
    float w3[16];
    #pragma unroll
    for (int b = 0; b < 16; b++) w3[b] = 0.0f;
    #pragma unroll
    for (int l = 0; l < 8; l++) {
      const float el = g.enc[l];
      const float4* pc = (const float4*)(sP + 4096 + (d*8 + l)*16);
      #pragma unroll
      for (int q = 0; q < 4; q++) {
        float4 f = pc[q];
        w3[4*q]+=el*f.x; w3[4*q+1]+=el*f.y; w3[4*q+2]+=el*f.z; w3[4*q+3]+=el*f.w;
      }
    }
    float W0=0, W1=0, W2=0;
    #pragma unroll
    for (int b = 0; b < 16; b++) { float w = w3[b]; W0 += w*V0[b]; W1 += w*V1[b]; W2 += w*V2[b]; }

    Q0[d] = A0 + (g.h1*W2 - g.h2*W1);
    Q1[d] = A1 + (g.h2*W0 - g.h0*W2);
    Q2[d] = A2 + (g.h0*W1 - g.h1*W0);
  }

  // phase 3: psi_d = (sum_l enc P022) (x) X + h_i Q_j + h_i h_j scd   (X held in regs, V/T dead)
  float X[72];
  #pragma unroll
  for (int q = 0; q < 18; q++) { float4 f = xd4[q]; X[4*q]=f.x; X[4*q+1]=f.y; X[4*q+2]=f.z; X[4*q+3]=f.w; }
  const float hh[3] = { g.h0, g.h1, g.h2 };
  float* o = outD + (size_t)ni*72;
  #pragma unroll 1
  for (int d = 0; d < 8; d++) {
    float w[8] = {0,0,0,0,0,0,0,0};
    #pragma unroll
    for (int l = 0; l < 8; l++) {
      const float el = g.enc[l];
      const float4* p = (const float4*)(sP + (d*8 + l)*8);
      float4 fa = p[0], fb = p[1];
      w[0]+=el*fa.x; w[1]+=el*fa.y; w[2]+=el*fa.z; w[3]+=el*fa.w;
      w[4]+=el*fb.x; w[5]+=el*fb.y; w[6]+=el*fb.z; w[7]+=el*fb.w;
    }
    float acc[9] = {0,0,0,0,0,0,0,0,0};
    #pragma unroll
    for (int b = 0; b < 8; b++) {
      const float wb = w[b];
      #pragma unroll
      for (int k = 0; k < 9; k++) acc[k] += wb*X[9*b+k];
    }
    const float sd = scd[d];
    const float q0 = Q0[d], q1 = Q1[d], q2 = Q2[d];
    const float qq[3] = { q0, q1, q2 };
    #pragma unroll
    for (int i = 0; i < 3; i++) {
      const float hi = hh[i];
      #pragma unroll
      for (int j = 0; j < 3; j++) {
        atomicAdd(o + d*9 + 3*i + j, 0.1f*(acc[3*i+j] + hi*qq[j] + hi*hh[j]*sd));
      }
    }
  }
}

extern "C" void kernel_launch(void* const* d_in, const int* in_sizes, int n_in,
                              void* d_out, int out_size, void* d_ws, size_t ws_size,
                              hipStream_t stream) {
  const float* r_ij = (const float*)d_in[0];
  const float* x_a  = (const float*)d_in[1];
  const float* x_v  = (const float*)d_in[2];
  const float* x_d  = (const float*)d_in[3];
  const float* P000 = (const float*)d_in[4];
  const float* P110 = (const float*)d_in[5];
  const float* P220 = (const float*)d_in[6];
  const float* P011 = (const float*)d_in[7];
  const float* P101 = (const float*)d_in[8];
  const float* P121 = (const float*)d_in[9];
  const float* P211 = (const float*)d_in[10];
  const float* P111 = (const float*)d_in[11];
  const float* P022 = (const float*)d_in[12];
  const float* P202 = (const float*)d_in[13];
  const float* P112 = (const float*)d_in[14];
  const float* P222 = (const float*)d_in[15];
  const float* P212 = (const float*)d_in[16];
  const int* src = (const int*)d_in[17];
  const int* dst = (const int*)d_in[18];

  const int E = in_sizes[17];
  const int N = in_sizes[1] / 32;
  float* out = (float*)d_out;
  float* outA = out;
  float* outV = out + (size_t)N*32;
  float* outD = out + (size_t)N*80;

  hipMemsetAsync(d_out, 0, (size_t)out_size * sizeof(float), stream);

  const size_t need = 256 + (size_t)E * sizeof(int);
  int* cnt = nullptr;
  int* list = nullptr;
  if (ws_size >= need) {
    cnt  = (int*)d_ws;
    list = (int*)((char*)d_ws + 256);
    hipMemsetAsync(d_ws, 0, 256, stream);
    compact_k<<<(E + 255)/256, 256, 0, stream>>>(r_ij, E, cnt, list);
  }

  msgA_k<<<(E + 511)/512, 512, 0, stream>>>(r_ij, x_a, x_v, x_d,
      P000, P110, P220, src, dst, cnt, list, E, outA);
  msgV_k<<<(E + 255)/256, 256, 0, stream>>>(r_ij, x_a, x_v, x_d,
      P011, P101, P121, P211, P111, src, dst, cnt, list, E, outV);
  msgD_k<<<(E + 255)/256, 256, 0, stream>>>(r_ij, x_a, x_v, x_d,
      P022, P202, P112, P222, P212, src, dst, cnt, list, E, outD);
}